// Round 5
// baseline (667.962 us; speedup 1.0000x reference)
//
#include <hip/hip_runtime.h>
#include <stdint.h>

// Problem constants (from reference)
#define NT 50000     // target cells
#define NS 100000    // source cells
#define NE 400000    // nonzeros per sparse operator
#define CIN 128
#define COUT 256
#define HL 264       // LDS h-buffer row stride in u16 (528B: 2-way-free LDS reads)
#define SROW 32      // stripe rows per block (4 blocks/CU)

typedef unsigned short u16;
typedef short bf8 __attribute__((ext_vector_type(8)));   // 8 bf16 (4 VGPRs)
typedef float f4 __attribute__((ext_vector_type(4)));    // 4 fp32 acc

__device__ __forceinline__ float bf2f(u16 u) {
  union { unsigned int i; float f; } x; x.i = ((unsigned int)u) << 16; return x.f;
}
__device__ __forceinline__ u16 f2bf(float f) {
  union { float f; unsigned int i; } x; x.f = f;
  return (u16)((x.i + 0x7fffu + ((x.i >> 16) & 1u)) >> 16);   // RNE
}
__device__ __forceinline__ float loadf(const void* base, size_t eoff, int f32) {
  if (f32) return ((const float*)base)[eoff];
  return bf2f(((const u16*)base)[eoff]);
}

// ---------------------------------------------------------------------------
// dtype detection (R3-proven logic) + cnt zeroing fused in (blocks >= 13).
// fp32 normal data has u32 exponent in [100,140]; bf16 pairs don't.
// ---------------------------------------------------------------------------
struct DetectArgs { const unsigned int* p[13]; int nw[13]; };

__global__ void detect_all(DetectArgs a, int* __restrict__ flags, int* __restrict__ cnt) {
  const int bi = blockIdx.x;
  if (bi >= 13) {                    // zero cnt[0 .. 2*NT)
    int t = ((bi - 13) * 256 + threadIdx.x) * 4;
    if (t < 2 * NT) *(int4*)&cnt[t] = (int4){0, 0, 0, 0};   // 2*NT % 4 == 0
    return;
  }
  __shared__ int s_sane, s_nz;
  const unsigned int* buf = a.p[bi];
  const int nw = a.nw[bi];
  if (threadIdx.x == 0) { s_sane = 0; s_nz = 0; }
  __syncthreads();
  int sane = 0, nz = 0;
  for (int i = threadIdx.x; i < nw; i += 256) {
    unsigned int w = buf[i];
    if (w != 0u) {
      ++nz;
      unsigned int e = (w >> 23) & 0xFFu;
      if (e >= 100u && e <= 140u) ++sane;
    }
  }
  atomicAdd(&s_sane, sane);
  atomicAdd(&s_nz, nz);
  __syncthreads();
  if (threadIdx.x == 0) flags[bi] = (s_nz > 0 && 2 * s_sane > s_nz) ? 1 : 0;
}

// ---------------------------------------------------------------------------
// ONE-dispatch weight/bias prep: 5 transposes + 3 bias converts (was 8
// dispatches). mode 1: dst[mat][n][k] = src[mat][k][n]; mode 0: copy.
// ---------------------------------------------------------------------------
struct PrepArgs {
  const void* src[8];
  u16* dst[8];
  int flagidx[8];
  int K[8], N[8], mode[8];
  int cum[9];
};

__global__ void prep_all(PrepArgs a, const int* __restrict__ flags) {
  int t = blockIdx.x * 256 + threadIdx.x;
  if (t >= a.cum[8]) return;
  int r = 0;
#pragma unroll
  for (int q = 0; q < 7; ++q)
    if (t >= a.cum[q + 1]) r = q + 1;
  int i = t - a.cum[r];
  int f32 = flags[a.flagidx[r]];
  if (a.mode[r]) {
    int K = a.K[r], N = a.N[r], kn = K * N;
    int mat = i / kn, ii = i - mat * kn;
    int n = ii / K, k = ii - n * K;
    size_t s = (size_t)mat * kn + (size_t)k * N + n;
    a.dst[r][i] = f32 ? f2bf(((const float*)a.src[r])[s]) : ((const u16*)a.src[r])[s];
  } else {
    a.dst[r][i] = f32 ? f2bf(((const float*)a.src[r])[i]) : ((const u16*)a.src[r])[i];
  }
}

// ---------------------------------------------------------------------------
// MFMA building blocks (compile-time K -> fully unrolled so LLVM can
// software-pipeline ds_read/global-load across MFMAs; R2 post-mortem:
// runtime-K loop exposed full LDS latency every k-step, 85% idle).
// Fragment addressing identical to the R0/R3-proven pattern.
// ---------------------------------------------------------------------------
template <int K, int LDB>
__device__ __forceinline__ void mm_ldsA(f4 (&acc)[2][4], const u16* __restrict__ src,
                                        const u16* __restrict__ Bt, int wn, int bcol0,
                                        int mrow, int krow) {
#pragma unroll
  for (int i = 0; i < 2; ++i)
#pragma unroll
    for (int j = 0; j < 4; ++j) acc[i][j] = (f4){0.f, 0.f, 0.f, 0.f};
  const u16* bp[4];
#pragma unroll
  for (int j = 0; j < 4; ++j)
    bp[j] = Bt + (size_t)(wn + j * 16 + mrow) * LDB + bcol0 + krow;
  const u16* ap = src + mrow * HL + krow;
#pragma unroll
  for (int k0 = 0; k0 < K; k0 += 32) {
    bf8 aF[2], bF[4];
#pragma unroll
    for (int i = 0; i < 2; ++i) aF[i] = *(const bf8*)(ap + i * 16 * HL + k0);
#pragma unroll
    for (int j = 0; j < 4; ++j) bF[j] = *(const bf8*)(bp[j] + k0);
#pragma unroll
    for (int i = 0; i < 2; ++i)
#pragma unroll
      for (int j = 0; j < 4; ++j)
        acc[i][j] = __builtin_amdgcn_mfma_f32_16x16x32_bf16(aF[i], bF[j], acc[i][j], 0, 0, 0);
  }
}

__device__ __forceinline__ void mm_glbA(f4 (&acc)[2][4], const u16* __restrict__ A,
                                        int m0, int M, const u16* __restrict__ Bt,
                                        int wn, int mrow, int krow) {
#pragma unroll
  for (int i = 0; i < 2; ++i)
#pragma unroll
    for (int j = 0; j < 4; ++j) acc[i][j] = (f4){0.f, 0.f, 0.f, 0.f};
  const u16* ap[2];
#pragma unroll
  for (int i = 0; i < 2; ++i) {
    int r = m0 + i * 16 + mrow;
    if (r >= M) r = M - 1;
    ap[i] = A + (size_t)r * CIN + krow;
  }
  const u16* bp[4];
#pragma unroll
  for (int j = 0; j < 4; ++j)
    bp[j] = Bt + (size_t)(wn + j * 16 + mrow) * CIN + krow;
#pragma unroll
  for (int k0 = 0; k0 < CIN; k0 += 32) {
    bf8 aF[2], bF[4];
#pragma unroll
    for (int i = 0; i < 2; ++i) aF[i] = *(const bf8*)(ap[i] + k0);
#pragma unroll
    for (int j = 0; j < 4; ++j) bF[j] = *(const bf8*)(bp[j] + k0);
#pragma unroll
    for (int i = 0; i < 2; ++i)
#pragma unroll
      for (int j = 0; j < 4; ++j)
        acc[i][j] = __builtin_amdgcn_mfma_f32_16x16x32_bf16(aF[i], bF[j], acc[i][j], 0, 0, 0);
  }
}

// ---------------------------------------------------------------------------
// FUSED per-stripe MLP chain. One block = one 32-row stripe through ALL
// layers of BOTH branches; h in LDS (double-buffered), branch-0 merge
// partial in registers. 32-row stripe -> 33.8KB LDS -> 4 blocks/CU.
// ---------------------------------------------------------------------------
__global__ __launch_bounds__(256, 4)
void fused_mlp(const u16* __restrict__ agg0, const u16* __restrict__ agg1,
               const u16* __restrict__ W0t, const u16* __restrict__ W1t,
               const u16* __restrict__ mW0t, const u16* __restrict__ mW1t,
               const u16* __restrict__ mbc,   // [2][3][256] canonical biases
               const u16* __restrict__ Wmt,   // [256][512] transposed merge W
               const u16* __restrict__ bmc,   // [256]
               const void* __restrict__ xt, const int* __restrict__ xtflag,
               void* __restrict__ out, const int* __restrict__ outflag, int M) {
  __shared__ __align__(16) u16 sX[SROW * HL];
  __shared__ __align__(16) u16 sY[SROW * HL];

  const int tid  = threadIdx.x;
  const int wave = tid >> 6;
  const int lane = tid & 63;
  const int m0   = blockIdx.x * SROW;
  const int wn   = wave * 64;          // wave's N-quadrant
  const int mrow = lane & 15;
  const int krow = (lane >> 4) * 8;
  const int erow = (lane >> 4) * 4;    // epilogue row base (+ i*16 + r)
  const int ecol = lane & 15;          // epilogue col base (+ wn + j*16)

  const int xf = *xtflag;

  f4 acc[2][4];

  // epilogue: acc -> LDS h-buffer (bf16), optional bias/relu/x_target
  auto epi = [&](u16* dst, const u16* bias, int relu, int addxt) {
#pragma unroll
    for (int j = 0; j < 4; ++j) {
      const int col = wn + ecol + j * 16;
      const float bv = bias ? bf2f(bias[col]) : 0.f;
#pragma unroll
      for (int i = 0; i < 2; ++i)
#pragma unroll
        for (int r = 0; r < 4; ++r) {
          const int row = erow + i * 16 + r;     // local 0..31
          float v = acc[i][j][r] + bv;
          if (addxt) {
            int rr = m0 + row; if (rr >= M) rr = M - 1;
            v += loadf(xt, (size_t)rr * COUT + col, xf);
          }
          if (relu) v = fmaxf(v, 0.f);
          dst[row * HL + col] = f2bf(v);
        }
    }
  };

  // ================= branch 0 =================
  mm_glbA(acc, agg0, m0, M, W0t, wn, mrow, krow);       // L1: agg0 @ W0
  epi(sY, nullptr, 0, 1);  __syncthreads();             // + x_target -> sY
  mm_ldsA<COUT, COUT>(acc, sY, mW0t,                 wn, 0, mrow, krow);
  epi(sX, mbc + 0 * COUT, 1, 0); __syncthreads();
  mm_ldsA<COUT, COUT>(acc, sX, mW0t + COUT * COUT,   wn, 0, mrow, krow);
  epi(sY, mbc + 1 * COUT, 1, 0); __syncthreads();
  mm_ldsA<COUT, COUT>(acc, sY, mW0t + 2 * COUT * COUT, wn, 0, mrow, krow);
  epi(sX, mbc + 2 * COUT, 1, 0); __syncthreads();       // h0 in sX

  // partial merge: accP = h0 @ WmTop (registers across branch 1)
  mm_ldsA<COUT, 512>(acc, sX, Wmt, wn, 0, mrow, krow);
  f4 accP[2][4];
#pragma unroll
  for (int i = 0; i < 2; ++i)
#pragma unroll
    for (int j = 0; j < 4; ++j) accP[i][j] = acc[i][j];

  // ================= branch 1 =================
  mm_glbA(acc, agg1, m0, M, W1t, wn, mrow, krow);       // L1: agg1 @ W1
  epi(sY, nullptr, 0, 1);  __syncthreads();
  mm_ldsA<COUT, COUT>(acc, sY, mW1t,                 wn, 0, mrow, krow);
  epi(sX, mbc + 3 * COUT, 1, 0); __syncthreads();
  mm_ldsA<COUT, COUT>(acc, sX, mW1t + COUT * COUT,   wn, 0, mrow, krow);
  epi(sY, mbc + 4 * COUT, 1, 0); __syncthreads();
  mm_ldsA<COUT, COUT>(acc, sY, mW1t + 2 * COUT * COUT, wn, 0, mrow, krow);
  epi(sX, mbc + 5 * COUT, 1, 0); __syncthreads();       // h1 in sX

  // merge bottom: acc = h1 @ WmBot, then out = acc + accP + bm
  mm_ldsA<COUT, 512>(acc, sX, Wmt, wn, COUT, mrow, krow);

  const int of = *outflag;
#pragma unroll
  for (int j = 0; j < 4; ++j) {
    const int col = wn + ecol + j * 16;
    const float bv = bf2f(bmc[col]);
#pragma unroll
    for (int i = 0; i < 2; ++i)
#pragma unroll
      for (int r = 0; r < 4; ++r) {
        const int rr = m0 + erow + i * 16 + r;
        if (rr < M) {
          const size_t idx = (size_t)rr * COUT + col;
          float v = acc[i][j][r] + accP[i][j][r] + bv;
          if (of) ((float*)out)[idx] = v;
          else    ((u16*)out)[idx] = f2bf(v);
        }
      }
  }
}

// ---------------------------------------------------------------------------
// CSR build: histogram -> 2-level exclusive scan -> scatter (sorted val/col)
// Segments: [0,NT) branch0 rows, [NT,2NT) branch1 rows. Positions cover [0,2E).
// ---------------------------------------------------------------------------
__global__ void hist_kernel(const int* __restrict__ rows0, const int* __restrict__ rows1,
                            int* __restrict__ cnt) {
  int t = blockIdx.x * 256 + threadIdx.x;
  if (t >= 2 * NE) return;
  int seg = (t < NE) ? rows0[t] : (NT + rows1[t - NE]);
  atomicAdd(&cnt[seg], 1);
}

__global__ void scanA(const int* __restrict__ cnt, int* __restrict__ incl,
                      int* __restrict__ bsum, int n) {
  __shared__ int sd[256];
  int t = threadIdx.x, g = blockIdx.x * 256 + t;
  int v = (g < n) ? cnt[g] : 0;
  sd[t] = v; __syncthreads();
  for (int o = 1; o < 256; o <<= 1) {
    int x = (t >= o) ? sd[t - o] : 0;
    __syncthreads();
    sd[t] += x;
    __syncthreads();
  }
  if (g < n) incl[g] = sd[t];
  if (t == 255) bsum[blockIdx.x] = sd[255];
}

__global__ void scanB(int* __restrict__ bsum, int nb) {
  __shared__ int sd[512];
  int t = threadIdx.x;
  int v = (t < nb) ? bsum[t] : 0;
  sd[t] = v; __syncthreads();
  for (int o = 1; o < 512; o <<= 1) {
    int x = (t >= o) ? sd[t - o] : 0;
    __syncthreads();
    sd[t] += x;
    __syncthreads();
  }
  if (t < nb) bsum[t] = sd[t] - v;   // exclusive block offsets
}

__global__ void scanC(int* __restrict__ cnt, const int* __restrict__ incl,
                      const int* __restrict__ bsum, int* __restrict__ row_ptr,
                      int n, int total) {
  int g = blockIdx.x * 256 + threadIdx.x;
  if (g == 0) row_ptr[n] = total;
  if (g >= n) return;
  row_ptr[g] = incl[g] - cnt[g] + bsum[blockIdx.x];
  cnt[g] = 0;                       // reset for scatter (replaces memset)
}

__global__ void scatter_kernel(const int* __restrict__ rows0, const int* __restrict__ cols0,
                               const void* __restrict__ vals0, const int* __restrict__ v0f,
                               const int* __restrict__ rows1, const int* __restrict__ cols1,
                               const void* __restrict__ vals1, const int* __restrict__ v1f,
                               const int* __restrict__ row_ptr, int* __restrict__ cnt,
                               int* __restrict__ scol, float* __restrict__ sval) {
  int t = blockIdx.x * 256 + threadIdx.x;
  if (t >= 2 * NE) return;
  int seg, col; float v;
  if (t < NE) { seg = rows0[t]; col = cols0[t]; v = loadf(vals0, t, *v0f); }
  else { int e = t - NE; seg = NT + rows1[e]; col = cols1[e]; v = loadf(vals1, e, *v1f); }
  int pos = row_ptr[seg] + atomicAdd(&cnt[seg], 1);
  scol[pos] = col;
  sval[pos] = v;
}

// ---------------------------------------------------------------------------
// Re-associated sparse aggregate: agg[t,:] = sum_e val_e * Xsrc[col_e,:]
// Reads x_src DIRECTLY (dtype-branched; drops the xsc convert round-trip).
// One wave/target row; lane covers 2 ch. fp32 acc; bf16 out.
// ---------------------------------------------------------------------------
__global__ __launch_bounds__(256)
void spmm_gather(const int* __restrict__ row_ptr, const int* __restrict__ scol,
                 const float* __restrict__ sval, const void* __restrict__ Xsrc,
                 const int* __restrict__ xsflag, u16* __restrict__ agg, int seg_base) {
  int wid = blockIdx.x * 4 + (threadIdx.x >> 6);
  int lane = threadIdx.x & 63;
  if (wid >= NT) return;
  int seg = seg_base + wid;
  int p0 = row_ptr[seg], p1 = row_ptr[seg + 1];
  int c = lane * 2;
  float a0 = 0.f, a1 = 0.f;
  int p = p0;
  if (*xsflag) {
    const float* X = (const float*)Xsrc;
    for (; p + 3 < p1; p += 4) {
      int c0 = scol[p], c1 = scol[p + 1], c2 = scol[p + 2], c3 = scol[p + 3];
      float v0 = sval[p], v1 = sval[p + 1], v2 = sval[p + 2], v3 = sval[p + 3];
      float2 s0 = *(const float2*)&X[(size_t)c0 * CIN + c];
      float2 s1 = *(const float2*)&X[(size_t)c1 * CIN + c];
      float2 s2 = *(const float2*)&X[(size_t)c2 * CIN + c];
      float2 s3 = *(const float2*)&X[(size_t)c3 * CIN + c];
      a0 += v0 * s0.x; a1 += v0 * s0.y;
      a0 += v1 * s1.x; a1 += v1 * s1.y;
      a0 += v2 * s2.x; a1 += v2 * s2.y;
      a0 += v3 * s3.x; a1 += v3 * s3.y;
    }
    for (; p < p1; ++p) {
      float v = sval[p];
      float2 s = *(const float2*)&X[(size_t)scol[p] * CIN + c];
      a0 += v * s.x; a1 += v * s.y;
    }
  } else {
    const u16* X = (const u16*)Xsrc;
    for (; p + 3 < p1; p += 4) {
      int c0 = scol[p], c1 = scol[p + 1], c2 = scol[p + 2], c3 = scol[p + 3];
      float v0 = sval[p], v1 = sval[p + 1], v2 = sval[p + 2], v3 = sval[p + 3];
      ushort2 s0 = *(const ushort2*)&X[(size_t)c0 * CIN + c];
      ushort2 s1 = *(const ushort2*)&X[(size_t)c1 * CIN + c];
      ushort2 s2 = *(const ushort2*)&X[(size_t)c2 * CIN + c];
      ushort2 s3 = *(const ushort2*)&X[(size_t)c3 * CIN + c];
      a0 += v0 * bf2f(s0.x); a1 += v0 * bf2f(s0.y);
      a0 += v1 * bf2f(s1.x); a1 += v1 * bf2f(s1.y);
      a0 += v2 * bf2f(s2.x); a1 += v2 * bf2f(s2.y);
      a0 += v3 * bf2f(s3.x); a1 += v3 * bf2f(s3.y);
    }
    for (; p < p1; ++p) {
      float v = sval[p];
      ushort2 s = *(const ushort2*)&X[(size_t)scol[p] * CIN + c];
      a0 += v * bf2f(s.x); a1 += v * bf2f(s.y);
    }
  }
  ushort2 o;
  o.x = f2bf(a0); o.y = f2bf(a1);
  *(ushort2*)&agg[(size_t)wid * CIN + c] = o;
}

// ---------------------------------------------------------------------------
extern "C" void kernel_launch(void* const* d_in, const int* in_sizes, int n_in,
                              void* d_out, int out_size, void* d_ws, size_t ws_size,
                              hipStream_t stream) {
  (void)n_in; (void)out_size; (void)ws_size;

  // ---- input ordering: R3-proven switch on in_sizes[0] ----
  int I_xt, I_xs0, I_xs1, I_v0, I_v1, I_r0, I_c0, I_r1, I_c1,
      I_W0, I_W1, I_mW0, I_mb0, I_mW1, I_mb1, I_Wm, I_bm;
  if (in_sizes[0] == 32768) {
    // alphabetical key order
    I_W0 = 0; I_W1 = 1; I_Wm = 2; I_bm = 3; I_c0 = 4; I_c1 = 5;
    I_mW0 = 6; I_mW1 = 7; I_mb0 = 8; I_mb1 = 9; I_r0 = 10; I_r1 = 11;
    I_v0 = 12; I_v1 = 13; I_xs0 = 14; I_xs1 = 15; I_xt = 16;
  } else {
    // dict / signature order
    I_xt = 0; I_xs0 = 1; I_xs1 = 2; I_v0 = 3; I_v1 = 4; I_r0 = 5; I_c0 = 6;
    I_r1 = 7; I_c1 = 8; I_W0 = 9; I_W1 = 10; I_mW0 = 11; I_mb0 = 12;
    I_mW1 = 13; I_mb1 = 14; I_Wm = 15; I_bm = 16;
  }
  const void* x_target = d_in[I_xt];
  const void* x_src0   = d_in[I_xs0];
  const void* x_src1   = d_in[I_xs1];
  const void* vals0    = d_in[I_v0];
  const void* vals1    = d_in[I_v1];
  const int* rows0     = (const int*)d_in[I_r0];
  const int* cols0     = (const int*)d_in[I_c0];
  const int* rows1     = (const int*)d_in[I_r1];
  const int* cols1     = (const int*)d_in[I_c1];
  const void* W0       = d_in[I_W0];
  const void* W1       = d_in[I_W1];
  const void* mW0      = d_in[I_mW0];
  const void* mb0      = d_in[I_mb0];
  const void* mW1      = d_in[I_mW1];
  const void* mb1      = d_in[I_mb1];
  const void* Wm       = d_in[I_Wm];
  const void* bm       = d_in[I_bm];

  // ---- workspace ----
  char* ws = (char*)d_ws;
  size_t off = 0;
  auto alloc = [&](size_t bytes) -> char* {
    off = (off + 255) & ~(size_t)255;
    char* p = ws + off;
    off += bytes;
    return p;
  };
  int* flags = (int*)alloc(16 * 4);   // 0=xt 1=xs0 2=xs1 3=v0 4=v1 5=W0 6=W1
                                      // 7=mW0 8=mb0 9=mW1 10=mb1 11=Wm 12=bm
  u16* W0t   = (u16*)alloc((size_t)COUT * CIN * 2);
  u16* W1t   = (u16*)alloc((size_t)COUT * CIN * 2);
  u16* mW0t  = (u16*)alloc((size_t)3 * COUT * COUT * 2);
  u16* mW1t  = (u16*)alloc((size_t)3 * COUT * COUT * 2);
  u16* Wmt   = (u16*)alloc((size_t)COUT * 512 * 2);
  u16* mbc   = (u16*)alloc((size_t)2 * 3 * COUT * 2);   // canonical biases
  u16* bmc   = (u16*)alloc((size_t)COUT * 2);
  u16* agg0  = (u16*)alloc((size_t)NT * CIN * 2);       // 12.8 MB
  u16* agg1  = (u16*)alloc((size_t)NT * CIN * 2);       // 12.8 MB
  int* cnt     = (int*)alloc((size_t)2 * NT * 4);
  int* row_ptr = (int*)alloc(((size_t)2 * NT + 1) * 4);
  int* incl    = (int*)alloc((size_t)2 * NT * 4);
  int* bsum    = (int*)alloc(512 * 4);
  int* scol    = (int*)alloc((size_t)2 * NE * 4);
  float* sval  = (float*)alloc((size_t)2 * NE * 4);

  // ---- dtype detection + cnt zeroing: ONE dispatch ----
  DetectArgs da;
  const void* dp[13]  = {x_target, x_src0, x_src1, vals0, vals1, W0, W1,
                         mW0, mb0, mW1, mb1, Wm, bm};
  const int   dn[13]  = {NT * COUT, NS * CIN, NS * CIN, NE, NE,
                         CIN * COUT, CIN * COUT, 3 * COUT * COUT, 3 * COUT,
                         3 * COUT * COUT, 3 * COUT, 512 * COUT, COUT};
  for (int i = 0; i < 13; ++i) {
    da.p[i] = (const unsigned int*)dp[i];
    int nw = dn[i] / 2; if (nw > 8192) nw = 8192; if (nw < 1) nw = 1;
    da.nw[i] = nw;
  }
  const int zb = (2 * NT + 1023) / 1024;   // 98 zero-blocks
  detect_all<<<13 + zb, 256, 0, stream>>>(da, flags, cnt);

  // ---- ONE-dispatch weight/bias canonicalization ----
  PrepArgs pa;
  const void* psrc[8] = {W0, W1, mW0, mW1, Wm, mb0, mb1, bm};
  u16* pdst[8]        = {W0t, W1t, mW0t, mW1t, Wmt, mbc, mbc + 3 * COUT, bmc};
  const int pflag[8]  = {5, 6, 7, 9, 11, 8, 10, 12};
  const int pK[8]     = {CIN, CIN, COUT, COUT, 512, 0, 0, 0};
  const int pN[8]     = {COUT, COUT, COUT, COUT, COUT, 0, 0, 0};
  const int pmode[8]  = {1, 1, 1, 1, 1, 0, 0, 0};
  const int ptot[8]   = {CIN * COUT, CIN * COUT, 3 * COUT * COUT, 3 * COUT * COUT,
                         512 * COUT, 3 * COUT, 3 * COUT, COUT};
  pa.cum[0] = 0;
  for (int i = 0; i < 8; ++i) {
    pa.src[i] = psrc[i]; pa.dst[i] = pdst[i]; pa.flagidx[i] = pflag[i];
    pa.K[i] = pK[i]; pa.N[i] = pN[i]; pa.mode[i] = pmode[i];
    pa.cum[i + 1] = pa.cum[i] + ptot[i];
  }
  prep_all<<<(pa.cum[8] + 255) / 256, 256, 0, stream>>>(pa, flags);

  // ---- CSR build over both operators (segments 0..2*NT) ----
  hist_kernel<<<(2 * NE + 255) / 256, 256, 0, stream>>>(rows0, rows1, cnt);
  const int nseg = 2 * NT;
  const int nb = (nseg + 255) / 256;     // 391
  scanA<<<nb, 256, 0, stream>>>(cnt, incl, bsum, nseg);
  scanB<<<1, 512, 0, stream>>>(bsum, nb);
  scanC<<<nb, 256, 0, stream>>>(cnt, incl, bsum, row_ptr, nseg, 2 * NE);
  scatter_kernel<<<(2 * NE + 255) / 256, 256, 0, stream>>>(
      rows0, cols0, vals0, flags + 3, rows1, cols1, vals1, flags + 4,
      row_ptr, cnt, scol, sval);

  // ---- per-branch aggregate (direct x_src read, dtype-branched) ----
  spmm_gather<<<NT / 4, 256, 0, stream>>>(row_ptr, scol, sval, x_src0, flags + 1, agg0, 0);
  spmm_gather<<<NT / 4, 256, 0, stream>>>(row_ptr, scol, sval, x_src1, flags + 2, agg1, NT);

  // ---- the entire 10-GEMM chain in ONE dispatch (32-row stripes) ----
  fused_mlp<<<(NT + SROW - 1) / SROW, 256, 0, stream>>>(
      agg0, agg1, W0t, W1t, mW0t, mW1t, mbc, Wmt, bmc,
      x_target, flags + 0, d_out, flags + 0, NT);
}